// Round 1
// baseline (226.425 us; speedup 1.0000x reference)
//
#include <hip/hip_runtime.h>
#include <hip/hip_bf16.h>

// Problem: Xp = X@p, Yp = Y@p (784 x 32768 fp32 mat-vec each), then gather
// 100 pixels from each 28x28 image via index pairs. Memory-bound: ~205 MB
// of X/Y traffic dominates. One block per row, float4 coalesced loads.

#define HW_PIX 784      // 28*28 rows per matrix
#define QDIM   32768    // inner dimension
#define Q4     (QDIM / 4)

__global__ __launch_bounds__(256) void matvec_rows(
        const float* __restrict__ X,
        const float* __restrict__ Y,
        const float* __restrict__ p,
        float* __restrict__ ws) {
    const int row = blockIdx.x;  // 0..1567: 0..783 -> X rows, 784..1567 -> Y rows
    const float* base = (row < HW_PIX)
        ? (X + (size_t)row * QDIM)
        : (Y + (size_t)(row - HW_PIX) * QDIM);
    const float4* __restrict__ b4 = (const float4*)base;
    const float4* __restrict__ p4 = (const float4*)p;

    float sum = 0.f;
    // 8192 float4 per row / 256 threads = 32 iterations, fully coalesced
    for (int i = threadIdx.x; i < Q4; i += 256) {
        float4 a = b4[i];
        float4 b = p4[i];
        sum += a.x * b.x + a.y * b.y + a.z * b.z + a.w * b.w;
    }

    // wave-64 shuffle reduction
    for (int off = 32; off > 0; off >>= 1)
        sum += __shfl_down(sum, off, 64);

    __shared__ float smem[4];
    const int lane = threadIdx.x & 63;
    const int wid  = threadIdx.x >> 6;
    if (lane == 0) smem[wid] = sum;
    __syncthreads();
    if (threadIdx.x == 0)
        ws[row] = smem[0] + smem[1] + smem[2] + smem[3];
}

__global__ void gather_dgms(
        const float* __restrict__ ws,     // ws[0..783]=Xp, ws[784..1567]=Yp
        const int* __restrict__ inds1,
        const int* __restrict__ inds2,
        float* __restrict__ out) {
    const int k = threadIdx.x;  // 0..99 point index
    if (k < 100) {
        int i1 = inds1[2 * k];
        int j1 = inds1[2 * k + 1];
        out[k] = ws[i1 * 28 + j1];
        int i2 = inds2[2 * k];
        int j2 = inds2[2 * k + 1];
        out[100 + k] = ws[HW_PIX + i2 * 28 + j2];
    }
}

extern "C" void kernel_launch(void* const* d_in, const int* in_sizes, int n_in,
                              void* d_out, int out_size, void* d_ws, size_t ws_size,
                              hipStream_t stream) {
    const float* X     = (const float*)d_in[0];
    const float* Y     = (const float*)d_in[1];
    const float* p     = (const float*)d_in[2];
    const int*   inds1 = (const int*)d_in[3];
    const int*   inds2 = (const int*)d_in[4];
    float* out = (float*)d_out;
    float* ws  = (float*)d_ws;   // needs 1568 floats (6.1 KB)

    matvec_rows<<<2 * HW_PIX, 256, 0, stream>>>(X, Y, p, ws);
    gather_dgms<<<1, 128, 0, stream>>>(ws, inds1, inds2, out);
}

// Round 2
// 180.058 us; speedup vs baseline: 1.2575x; 1.2575x over previous
//
#include <hip/hip_runtime.h>
#include <hip/hip_bf16.h>

// Key insight: the reference only returns Xp/Yp at <=100 gathered pixels per
// image. So instead of 1568 full row-dots (205 MB), compute only the 200
// selected rows (25.6 MB). Indices are on device -> resolve row per block.
//
// Grid: 200 outputs x SPLIT chunk-blocks. Each block dots a 16 KB chunk of
// row M[row,:] against p, block-reduces, atomicAdds into out[k].

#define QDIM   32768
#define SPLIT  8
#define CHUNK4 (QDIM / SPLIT / 4)   // 1024 float4 per chunk; 4 per thread

__global__ __launch_bounds__(256) void dot_gather(
        const float* __restrict__ X,
        const float* __restrict__ Y,
        const float* __restrict__ p,
        const int* __restrict__ inds1,
        const int* __restrict__ inds2,
        float* __restrict__ out) {
    const int b = blockIdx.x;
    const int k = b >> 3;           // output index 0..199 (SPLIT=8)
    const int c = b & 7;            // chunk index 0..7

    int i, j;
    const float* M;
    if (k < 100) {
        i = inds1[2 * k];
        j = inds1[2 * k + 1];
        M = X;
    } else {
        const int kk = k - 100;
        i = inds2[2 * kk];
        j = inds2[2 * kk + 1];
        M = Y;
    }
    const int row = i * 28 + j;

    const float4* __restrict__ a4 =
        (const float4*)(M + (size_t)row * QDIM) + (size_t)c * CHUNK4;
    const float4* __restrict__ p4 =
        (const float4*)p + (size_t)c * CHUNK4;

    // 4 independent float4 pairs in flight per thread (8 loads), then FMA.
    const int t = threadIdx.x;
    float4 a0 = a4[t];
    float4 b0 = p4[t];
    float4 a1 = a4[t + 256];
    float4 b1 = p4[t + 256];
    float4 a2 = a4[t + 512];
    float4 b2 = p4[t + 512];
    float4 a3 = a4[t + 768];
    float4 b3 = p4[t + 768];

    float s0 = a0.x * b0.x + a0.y * b0.y + a0.z * b0.z + a0.w * b0.w;
    float s1 = a1.x * b1.x + a1.y * b1.y + a1.z * b1.z + a1.w * b1.w;
    float s2 = a2.x * b2.x + a2.y * b2.y + a2.z * b2.z + a2.w * b2.w;
    float s3 = a3.x * b3.x + a3.y * b3.y + a3.z * b3.z + a3.w * b3.w;
    float sum = (s0 + s1) + (s2 + s3);

    // wave-64 shuffle reduction
    for (int off = 32; off > 0; off >>= 1)
        sum += __shfl_down(sum, off, 64);

    __shared__ float smem[4];
    const int lane = t & 63;
    const int wid  = t >> 6;
    if (lane == 0) smem[wid] = sum;
    __syncthreads();
    if (t == 0) {
        float blk = (smem[0] + smem[1]) + (smem[2] + smem[3]);
        atomicAdd(out + k, blk);
    }
}

extern "C" void kernel_launch(void* const* d_in, const int* in_sizes, int n_in,
                              void* d_out, int out_size, void* d_ws, size_t ws_size,
                              hipStream_t stream) {
    const float* X     = (const float*)d_in[0];
    const float* Y     = (const float*)d_in[1];
    const float* p     = (const float*)d_in[2];
    const int*   inds1 = (const int*)d_in[3];
    const int*   inds2 = (const int*)d_in[4];
    float* out = (float*)d_out;

    // d_out is poisoned 0xAA before every call -> zero it (capturable).
    hipMemsetAsync(out, 0, 200 * sizeof(float), stream);
    dot_gather<<<200 * SPLIT, 256, 0, stream>>>(X, Y, p, inds1, inds2, out);
}

// Round 3
// 179.324 us; speedup vs baseline: 1.2627x; 1.0041x over previous
//
#include <hip/hip_runtime.h>
#include <hip/hip_bf16.h>

// Single-dispatch version. The reference output is only the 200 gathered
// pixels of Xp/Yp, so we compute exactly those 200 row-dots (<=25 MB of X/Y
// traffic vs 205 MB for the full matvec). One block per output element:
// block k resolves its (i,j) index (block-uniform -> scalar loads), dots
// row M[i*28+j, :] (32768 fp32 = 128 KB) against p with float4 loads,
// block-reduces, and stores out[k] directly. No atomics, no memset, one
// launch -- the harness's own reset fills/copies (~160 us) dominate dur_us.

#define QDIM   32768
#define Q4     (QDIM / 4)      // 8192 float4 per row
#define NPTS   100             // points per diagram

__global__ __launch_bounds__(256) void dot_gather(
        const float* __restrict__ X,
        const float* __restrict__ Y,
        const float* __restrict__ p,
        const int* __restrict__ inds1,
        const int* __restrict__ inds2,
        float* __restrict__ out) {
    const int k = blockIdx.x;   // 0..199

    int i, j;
    const float* M;
    if (k < NPTS) {
        i = inds1[2 * k];
        j = inds1[2 * k + 1];
        M = X;
    } else {
        const int kk = k - NPTS;
        i = inds2[2 * kk];
        j = inds2[2 * kk + 1];
        M = Y;
    }
    const int row = i * 28 + j;

    const float4* __restrict__ a4 = (const float4*)(M + (size_t)row * QDIM);
    const float4* __restrict__ p4 = (const float4*)p;

    const int t = threadIdx.x;
    float s0 = 0.f, s1 = 0.f, s2 = 0.f, s3 = 0.f;
    // 8192 float4 / 256 threads = 32 iterations; unroll for load ILP.
#pragma unroll 8
    for (int i4 = 0; i4 < Q4 / 256; i4 += 4) {
        float4 a0 = a4[t + (i4 + 0) * 256];
        float4 b0 = p4[t + (i4 + 0) * 256];
        float4 a1 = a4[t + (i4 + 1) * 256];
        float4 b1 = p4[t + (i4 + 1) * 256];
        float4 a2 = a4[t + (i4 + 2) * 256];
        float4 b2 = p4[t + (i4 + 2) * 256];
        float4 a3 = a4[t + (i4 + 3) * 256];
        float4 b3 = p4[t + (i4 + 3) * 256];
        s0 += a0.x * b0.x + a0.y * b0.y + a0.z * b0.z + a0.w * b0.w;
        s1 += a1.x * b1.x + a1.y * b1.y + a1.z * b1.z + a1.w * b1.w;
        s2 += a2.x * b2.x + a2.y * b2.y + a2.z * b2.z + a2.w * b2.w;
        s3 += a3.x * b3.x + a3.y * b3.y + a3.z * b3.z + a3.w * b3.w;
    }
    float sum = (s0 + s1) + (s2 + s3);

    // wave-64 shuffle reduction
    for (int off = 32; off > 0; off >>= 1)
        sum += __shfl_down(sum, off, 64);

    __shared__ float smem[4];
    const int lane = t & 63;
    const int wid  = t >> 6;
    if (lane == 0) smem[wid] = sum;
    __syncthreads();
    if (t == 0)
        out[k] = (smem[0] + smem[1]) + (smem[2] + smem[3]);
}

extern "C" void kernel_launch(void* const* d_in, const int* in_sizes, int n_in,
                              void* d_out, int out_size, void* d_ws, size_t ws_size,
                              hipStream_t stream) {
    const float* X     = (const float*)d_in[0];
    const float* Y     = (const float*)d_in[1];
    const float* p     = (const float*)d_in[2];
    const int*   inds1 = (const int*)d_in[3];
    const int*   inds2 = (const int*)d_in[4];
    float* out = (float*)d_out;

    dot_gather<<<2 * NPTS, 256, 0, stream>>>(X, Y, p, inds1, inds2, out);
}